// Round 6
// baseline (185.401 us; speedup 1.0000x reference)
//
#include <hip/hip_runtime.h>

// MCLLoss: masked L1 loss over 5 overlapping value-ranges of real_img.
// Ranges: (-1,1), (-1,-.5), (-.5,0), (0,.5), (.5,1) — inclusive bounds,
// masks overlap; class_mask takes the LAST matching range index.
// Output layout: [loss, losses[5], class_mask_rescaled[N]]; rescale = cls*0.5-1.
//
// R11: fence-free fused final (kill the 2nd compute node).
// Ledger across R5-R10: C ~= 86us fixed (R8, the no-final-node round), and the
// final kernel + inter-node gap costs ~19-24us REGARDLESS of the final's
// internals -> the cost is the dependent dispatch itself. R8's fusion failed
// because __threadfence() = per-block L2 writeback (~1ms total). This version
// needs NO fence:
//  - partials: relaxed AGENT-scope atomicAdd into 256 banks (atomics execute
//    at the coherent point; cross-XCD correctness proven R2/R5, coherent
//    reader proven R8).
//  - ordering (my bank adds visible before my ticket add): ack-wait on my own
//    atomics (s_waitcnt vmcnt(0) = wait for RMW returns) — waits on 10 of MY
//    ops, not an L2 flush.
//  - ticket: two-level (64 sub-tickets depth 128 -> root depth 64) to avoid
//    R2's single-address depth-8192 chain (~100us).
//  - winner block reduces the 256 banks hot with relaxed agent loads.
// Main loop = R5 shape (proven 63-64us): 8192 blocks x 2 float4-pairs, all
// loads upfront, plain float2 mask stores, counts as floats (exact < 2^24).

#define TPB    256
#define NBANK  256
#define BANK_F 16   // floats per bank (64B line): sums [0..4], counts [5..9]

__device__ __forceinline__ void proc_elem(float pv, float rv,
                                          float s[5], float c[5], float& ov)
{
    float d = fabsf(pv - rv);
    bool geM1  = rv >= -1.0f;
    bool leM05 = rv <= -0.5f;
    bool geM05 = rv >= -0.5f;
    bool le0   = rv <=  0.0f;
    bool ge0   = rv >=  0.0f;
    bool le05  = rv <=  0.5f;
    bool ge05  = rv >=  0.5f;
    bool le1   = rv <=  1.0f;
    bool in0 = geM1  && le1;
    bool in1 = geM1  && leM05;
    bool in2 = geM05 && le0;
    bool in3 = ge0   && le05;
    bool in4 = ge05  && le1;
    s[0] += in0 ? d : 0.f;  c[0] += in0 ? 1.f : 0.f;
    s[1] += in1 ? d : 0.f;  c[1] += in1 ? 1.f : 0.f;
    s[2] += in2 ? d : 0.f;  c[2] += in2 ? 1.f : 0.f;
    s[3] += in3 ? d : 0.f;  c[3] += in3 ? 1.f : 0.f;
    s[4] += in4 ? d : 0.f;  c[4] += in4 ? 1.f : 0.f;
    // class value directly as float: -1, -.5, 0, .5, 1 (last matching wins)
    ov = in4 ? 1.0f : (in3 ? 0.5f : (in2 ? 0.0f : (in1 ? -0.5f : -1.0f)));
}

__device__ __forceinline__ void proc_group(int i, const float4& p, const float4& r,
                                           float s[5], float c[5],
                                           float* __restrict__ mask_out)
{
    float ov0, ov1, ov2, ov3;
    proc_elem(p.x, r.x, s, c, ov0);
    proc_elem(p.y, r.y, s, c, ov1);
    proc_elem(p.z, r.z, s, c, ov2);
    proc_elem(p.w, r.w, s, c, ov3);
    // mask_out = out+6: 8-byte aligned only -> float2 stores
    float2* mo = (float2*)(mask_out + 4 * (size_t)i);
    mo[0] = make_float2(ov0, ov1);
    mo[1] = make_float2(ov2, ov3);
}

__global__ __launch_bounds__(TPB, 8) void mcl_main(
    const float* __restrict__ pre, const float* __restrict__ real,
    float* __restrict__ out, float* __restrict__ acc,
    unsigned int* __restrict__ tick1, unsigned int* __restrict__ tick2,
    int n4, int n, int nblocks)
{
    float* mask_out = out + 6;
    float s[5] = {0.f, 0.f, 0.f, 0.f, 0.f};
    float c[5] = {0.f, 0.f, 0.f, 0.f, 0.f};

    const int t = threadIdx.x;
    const int i0 = blockIdx.x * 512 + t;   // block covers 512 float4 (8 KB)
    const int i1 = i0 + 256;
    const bool v0 = i0 < n4;
    const bool v1 = i1 < n4;

    const float4* pre4  = (const float4*)pre;
    const float4* real4 = (const float4*)real;

    // all four 16B loads upfront: one memory round-trip per thread (R5 shape)
    float4 p0, r0, p1, r1;
    if (v0) { p0 = pre4[i0]; r0 = real4[i0]; }
    if (v1) { p1 = pre4[i1]; r1 = real4[i1]; }

    if (v0) proc_group(i0, p0, r0, s, c, mask_out);
    if (v1) proc_group(i1, p1, r1, s, c, mask_out);

    // scalar tail (n not divisible by 4)
    {
        int tail_base = n4 * 4;
        int tail = n - tail_base;
        int gtid = blockIdx.x * TPB + t;
        if (gtid < tail) {
            int idx = tail_base + gtid;
            float ov;
            proc_elem(pre[idx], real[idx], s, c, ov);
            mask_out[idx] = ov;
        }
    }

    // wave64 butterfly reduction (10 floats)
#pragma unroll
    for (int j = 0; j < 5; ++j) {
#pragma unroll
        for (int off = 32; off > 0; off >>= 1) {
            s[j] += __shfl_down(s[j], off, 64);
            c[j] += __shfl_down(c[j], off, 64);
        }
    }

    __shared__ float ls[4][5];
    __shared__ float lc[4][5];
    __shared__ unsigned int lastflag;
    const int lane = t & 63;
    const int wave = t >> 6;
    if (lane == 0) {
#pragma unroll
        for (int j = 0; j < 5; ++j) { ls[wave][j] = s[j]; lc[wave][j] = c[j]; }
    }
    if (t == 0) lastflag = 0u;
    __syncthreads();

    // 10 lanes of wave 0: relaxed agent-scope atomic adds into this block's
    // bank (8192 blocks / 256 banks -> chain depth 32, proven-free regime).
    if (t < 10) {
        int j = (t < 5) ? t : t - 5;
        float v = (t < 5) ? (ls[0][j] + ls[1][j] + ls[2][j] + ls[3][j])
                          : (lc[0][j] + lc[1][j] + lc[2][j] + lc[3][j]);
        float* bank = acc + (size_t)(blockIdx.x & (NBANK - 1)) * BANK_F;
        float r = __hip_atomic_fetch_add(&bank[t], v, __ATOMIC_RELAXED,
                                         __HIP_MEMORY_SCOPE_AGENT);
        // keep the return live: forces the compiler to materialize the ack
        asm volatile("" :: "v"(r) : "memory");
    }

    // ticket chain (wave 0 only; same wave as the bank adds, so the waitcnt
    // drains OUR 10 RMWs — this is the whole ordering mechanism, no fence).
    if (t == 0) {
        asm volatile("s_waitcnt vmcnt(0)" ::: "memory");
        int sub = blockIdx.x & 63;
        unsigned cnt_s = ((unsigned)(nblocks - 1 - sub) >> 6) + 1u; // blocks in this sub-group
        unsigned o1 = __hip_atomic_fetch_add(&tick1[sub], 1u, __ATOMIC_RELAXED,
                                             __HIP_MEMORY_SCOPE_AGENT);
        if (o1 == cnt_s - 1u) {          // last arriver of this sub-group
            unsigned nsub = (nblocks < 64) ? (unsigned)nblocks : 64u;
            unsigned o2 = __hip_atomic_fetch_add(tick2, 1u, __ATOMIC_RELAXED,
                                                 __HIP_MEMORY_SCOPE_AGENT);
            if (o2 == nsub - 1u) lastflag = 1u;   // globally last
        }
    }
    __syncthreads();

    if (lastflag) {
        // winner block: thread t owns bank t — 10 coherent loads each
        // (relaxed agent loads bypass the non-coherent L1/L2; proven R8)
        float v[10];
        const float* bank = acc + (size_t)t * BANK_F;
#pragma unroll
        for (int j = 0; j < 10; ++j)
            v[j] = __hip_atomic_load(&bank[j], __ATOMIC_RELAXED,
                                     __HIP_MEMORY_SCOPE_AGENT);
#pragma unroll
        for (int j = 0; j < 10; ++j) {
#pragma unroll
            for (int off = 32; off > 0; off >>= 1)
                v[j] += __shfl_down(v[j], off, 64);
        }
        __shared__ float fs[4][10];
        if (lane == 0) {
#pragma unroll
            for (int j = 0; j < 10; ++j) fs[wave][j] = v[j];
        }
        __syncthreads();
        if (t == 0) {
            float total = 0.f;
#pragma unroll
            for (int j = 0; j < 5; ++j) {
                float ssum = fs[0][j] + fs[1][j] + fs[2][j] + fs[3][j];
                float csum = fs[0][5 + j] + fs[1][5 + j] + fs[2][5 + j] + fs[3][5 + j];
                float denom = csum > 1.f ? csum : 1.f;     // max(count, 1)
                float lv = (csum == 0.f) ? 0.f : (ssum / denom) * 0.2f;
                out[1 + j] = lv;
                total += lv;
            }
            out[0] = total;   // plain stores: kernel-end release makes them host-visible
        }
    }
}

extern "C" void kernel_launch(void* const* d_in, const int* in_sizes, int n_in,
                              void* d_out, int out_size, void* d_ws, size_t ws_size,
                              hipStream_t stream) {
    const float* pre  = (const float*)d_in[0];
    const float* real = (const float*)d_in[1];
    float* out = (float*)d_out;
    int n = in_sizes[0];
    int n4 = n / 4;

    int blocks = (n4 + 511) / 512;                 // 8192 for N=16M
    if (blocks < 1) blocks = 1;

    // d_ws layout: banks[256*16] floats | tick1[64] | tick2[1]
    float* acc = (float*)d_ws;
    unsigned int* tick1 = (unsigned int*)(acc + NBANK * BANK_F);
    unsigned int* tick2 = tick1 + 64;

    // d_ws re-poisoned to 0xAA before every timed call — zero banks + tickets.
    (void)hipMemsetAsync(d_ws, 0,
                         NBANK * BANK_F * sizeof(float) + 65 * sizeof(unsigned int),
                         stream);

    mcl_main<<<blocks, TPB, 0, stream>>>(pre, real, out, acc, tick1, tick2,
                                         n4, n, blocks);
}

// Round 7
// 176.291 us; speedup vs baseline: 1.0517x; 1.0517x over previous
//
#include <hip/hip_runtime.h>

// MCLLoss: masked L1 loss over 5 overlapping value-ranges of real_img.
// Ranges: (-1,1), (-1,-.5), (-.5,0), (0,.5), (.5,1) — inclusive bounds,
// masks overlap; class_mask takes the LAST matching range index.
// Output layout: [loss, losses[5], class_mask_rescaled[N]]; rescale = cls*0.5-1.
//
// R12: break the main kernel's phase-lock.
// Ledger across R5-R11: total - main = 112±5us for EVERY structure (3-node,
// 2-node, fused) -> fixed harness overhead, not attackable. Main is the only
// lever. Main's pipes are all <35% busy (HBM 33%, VALU 25%, DS small): the
// burst-load-then-compute shape phase-locks resident waves (memory idle
// during compute phase and vice versa) -> T_mem + T_valu instead of max.
// R6/R7's batching serialized because loads were issued in the iteration
// that consumes them (VGPR=24 = no tiles in flight across compute).
// Fix: explicit depth-3 software pipeline, loads unconditional (grid divides
// N exactly -> no bounds checks in fast path, compiler free to hoist):
// preload 3 tiles, then issue tile k+3 BEFORE computing tile k.
// 2048 blocks x 256 thr x 8 tiles: exactly one residency generation
// (8 blocks/CU), zero dispatch tail.
// Partials: plain-store SoA + separate vectorized final (R10 structure,
// no memset node; cross-dispatch visibility proven R9/R10).

#define TPB    256
#define GROUPS 8
#define SPAN   (TPB * GROUPS)   // 2048 float4 per block

__device__ __forceinline__ void proc_elem(float pv, float rv,
                                          float s[5], float c[5], float& ov)
{
    float d = fabsf(pv - rv);
    bool geM1  = rv >= -1.0f;
    bool leM05 = rv <= -0.5f;
    bool geM05 = rv >= -0.5f;
    bool le0   = rv <=  0.0f;
    bool ge0   = rv >=  0.0f;
    bool le05  = rv <=  0.5f;
    bool ge05  = rv >=  0.5f;
    bool le1   = rv <=  1.0f;
    bool in0 = geM1  && le1;
    bool in1 = geM1  && leM05;
    bool in2 = geM05 && le0;
    bool in3 = ge0   && le05;
    bool in4 = ge05  && le1;
    s[0] += in0 ? d : 0.f;  c[0] += in0 ? 1.f : 0.f;
    s[1] += in1 ? d : 0.f;  c[1] += in1 ? 1.f : 0.f;
    s[2] += in2 ? d : 0.f;  c[2] += in2 ? 1.f : 0.f;
    s[3] += in3 ? d : 0.f;  c[3] += in3 ? 1.f : 0.f;
    s[4] += in4 ? d : 0.f;  c[4] += in4 ? 1.f : 0.f;
    // class value directly as float: -1, -.5, 0, .5, 1 (last matching wins)
    ov = in4 ? 1.0f : (in3 ? 0.5f : (in2 ? 0.0f : (in1 ? -0.5f : -1.0f)));
}

__device__ __forceinline__ void proc_group(int i, const float4& p, const float4& r,
                                           float s[5], float c[5],
                                           float* __restrict__ mask_out)
{
    float ov0, ov1, ov2, ov3;
    proc_elem(p.x, r.x, s, c, ov0);
    proc_elem(p.y, r.y, s, c, ov1);
    proc_elem(p.z, r.z, s, c, ov2);
    proc_elem(p.w, r.w, s, c, ov3);
    // mask_out = out+6: 8-byte aligned only -> float2 stores
    float2* mo = (float2*)(mask_out + 4 * (size_t)i);
    mo[0] = make_float2(ov0, ov1);
    mo[1] = make_float2(ov2, ov3);
}

__global__ __launch_bounds__(TPB, 8) void mcl_main(
    const float* __restrict__ pre, const float* __restrict__ real,
    float* __restrict__ mask_out, float* __restrict__ acc, int n4, int n)
{
    float s[5] = {0.f, 0.f, 0.f, 0.f, 0.f};
    float c[5] = {0.f, 0.f, 0.f, 0.f, 0.f};

    const int t = threadIdx.x;
    const int bid = blockIdx.x;
    const int base = bid * SPAN + t;

    const float4* pre4  = (const float4*)pre;
    const float4* real4 = (const float4*)real;

    const bool full = (bid + 1) * SPAN <= n4;   // grid divides N=16M exactly
    if (full) {
        // depth-3 software pipeline, every load unconditional.
        // Preload tiles 0..2; steady state issues tile k+3 before computing k.
        float4 P0 = pre4[base + 0 * TPB], R0 = real4[base + 0 * TPB];
        float4 P1 = pre4[base + 1 * TPB], R1 = real4[base + 1 * TPB];
        float4 P2 = pre4[base + 2 * TPB], R2 = real4[base + 2 * TPB];

        float4 P3 = pre4[base + 3 * TPB], R3 = real4[base + 3 * TPB];
        proc_group(base + 0 * TPB, P0, R0, s, c, mask_out);
        float4 P4 = pre4[base + 4 * TPB], R4 = real4[base + 4 * TPB];
        proc_group(base + 1 * TPB, P1, R1, s, c, mask_out);
        float4 P5 = pre4[base + 5 * TPB], R5 = real4[base + 5 * TPB];
        proc_group(base + 2 * TPB, P2, R2, s, c, mask_out);
        float4 P6 = pre4[base + 6 * TPB], R6 = real4[base + 6 * TPB];
        proc_group(base + 3 * TPB, P3, R3, s, c, mask_out);
        float4 P7 = pre4[base + 7 * TPB], R7 = real4[base + 7 * TPB];
        proc_group(base + 4 * TPB, P4, R4, s, c, mask_out);
        proc_group(base + 5 * TPB, P5, R5, s, c, mask_out);
        proc_group(base + 6 * TPB, P6, R6, s, c, mask_out);
        proc_group(base + 7 * TPB, P7, R7, s, c, mask_out);
    } else {
        // partial block (unused when SPAN | n4): guarded loop
        for (int k = 0; k < GROUPS; ++k) {
            int i = base + k * TPB;
            if (i < n4) {
                float4 p = pre4[i], r = real4[i];
                proc_group(i, p, r, s, c, mask_out);
            }
        }
    }

    // scalar tail (n not divisible by 4) — last block only
    if (bid == (int)gridDim.x - 1) {
        int tail_base = n4 * 4;
        int tail = n - tail_base;
        if (t < tail) {
            int idx = tail_base + t;
            float ov;
            proc_elem(pre[idx], real[idx], s, c, ov);
            mask_out[idx] = ov;
        }
    }

    // wave64 butterfly reduction (10 floats)
#pragma unroll
    for (int j = 0; j < 5; ++j) {
#pragma unroll
        for (int off = 32; off > 0; off >>= 1) {
            s[j] += __shfl_down(s[j], off, 64);
            c[j] += __shfl_down(c[j], off, 64);
        }
    }

    __shared__ float ls[4][5];
    __shared__ float lc[4][5];
    const int lane = t & 63;
    const int wave = t >> 6;
    if (lane == 0) {
#pragma unroll
        for (int j = 0; j < 5; ++j) { ls[wave][j] = s[j]; lc[wave][j] = c[j]; }
    }
    __syncthreads();

    // plain store of 10 partials into this block's private SoA slots.
    if (t < 10) {
        int j = (t < 5) ? t : t - 5;
        float v = (t < 5) ? (ls[0][j] + ls[1][j] + ls[2][j] + ls[3][j])
                          : (lc[0][j] + lc[1][j] + lc[2][j] + lc[3][j]);
        acc[(size_t)t * gridDim.x + bid] = v;
    }
}

__global__ __launch_bounds__(1024) void mcl_final(
    const float* __restrict__ acc, float* __restrict__ out, int nblocks)
{
    const int t = threadIdx.x;
    float sum[10];
#pragma unroll
    for (int j = 0; j < 10; ++j) sum[j] = 0.f;

    if ((nblocks & 3) == 0) {
        // vector path: plane j = nblocks contiguous floats, 16B-aligned;
        // all 10 planes batched -> 10 concurrent float4 loads per iteration
        const int n4p = nblocks >> 2;
        for (int k4 = t; k4 < n4p; k4 += 1024) {
            float4 tmp[10];
#pragma unroll
            for (int j = 0; j < 10; ++j)
                tmp[j] = ((const float4*)(acc + (size_t)j * nblocks))[k4];
#pragma unroll
            for (int j = 0; j < 10; ++j)
                sum[j] += (tmp[j].x + tmp[j].y) + (tmp[j].z + tmp[j].w);
        }
    } else {
        for (int slot = t; slot < nblocks; slot += 1024) {
#pragma unroll
            for (int j = 0; j < 10; ++j)
                sum[j] += acc[(size_t)j * nblocks + slot];
        }
    }

    // wave butterfly
#pragma unroll
    for (int j = 0; j < 10; ++j) {
#pragma unroll
        for (int off = 32; off > 0; off >>= 1)
            sum[j] += __shfl_down(sum[j], off, 64);
    }

    __shared__ float fs[16][10];
    const int lane = t & 63;
    const int wave = t >> 6;
    if (lane == 0) {
#pragma unroll
        for (int j = 0; j < 10; ++j) fs[wave][j] = sum[j];
    }
    __syncthreads();

    __shared__ float red[10];
    if (t < 10) {
        float v = 0.f;
#pragma unroll
        for (int w = 0; w < 16; ++w) v += fs[w][t];
        red[t] = v;
    }
    __syncthreads();

    if (t == 0) {
        float total = 0.f;
#pragma unroll
        for (int j = 0; j < 5; ++j) {
            float ssum = red[j];
            float csum = red[5 + j];                  // exact integer-valued float
            float denom = csum > 1.f ? csum : 1.f;    // max(count, 1)
            float lv = (csum == 0.f) ? 0.f : (ssum / denom) * 0.2f;
            out[1 + j] = lv;
            total += lv;
        }
        out[0] = total;
    }
}

extern "C" void kernel_launch(void* const* d_in, const int* in_sizes, int n_in,
                              void* d_out, int out_size, void* d_ws, size_t ws_size,
                              hipStream_t stream) {
    const float* pre  = (const float*)d_in[0];
    const float* real = (const float*)d_in[1];
    float* out = (float*)d_out;
    int n = in_sizes[0];
    int n4 = n / 4;

    int blocks = (n4 + SPAN - 1) / SPAN;           // 2048 for N=16M (exact)
    if (blocks < 1) blocks = 1;

    // d_ws: 10 planes x nblocks floats (80 KB). Every slot the final kernel
    // reads is written by mcl_main first — no memset node needed.
    float* acc = (float*)d_ws;

    mcl_main<<<blocks, TPB, 0, stream>>>(pre, real, out + 6, acc, n4, n);
    mcl_final<<<1, 1024, 0, stream>>>(acc, out, blocks);
}